// Round 6
// baseline (150.825 us; speedup 1.0000x reference)
//
#include <hip/hip_runtime.h>
#include <hip/hip_bf16.h>
#include <math.h>

#define B_ 4
#define C_ 2
#define F_ 512
#define W_ 1024
#define NH_ 8
#define HD_ 64
#define ROT_ 32
#define NFREQ_ 16
#define BC_ (B_*C_)

// sqrt( (1/sqrt(512)) * log2(e) ): folded into Q and K so p = exp2(raw mfma dot)
#define QSC_ 0.2525048f

typedef short bf16x8 __attribute__((ext_vector_type(8)));
typedef float f32x4  __attribute__((ext_vector_type(4)));
typedef float f32x16 __attribute__((ext_vector_type(16)));
typedef unsigned short u16;
typedef unsigned int   u32;

#if __has_builtin(__builtin_amdgcn_exp2f)
#define EXP2(x) __builtin_amdgcn_exp2f(x)
#else
#define EXP2(x) exp2f(x)
#endif

// Explicit LDS-DMA drain before the publishing barrier (round-4 race fix):
// __syncthreads()' implicit drain does NOT reliably cover global_load_lds
// when consumers target a different LDS buffer (double-buffering).
#define VDRAIN() asm volatile("s_waitcnt vmcnt(0)" ::: "memory")

__device__ __forceinline__ u16 f2bf(float f) {
    union { float f; u32 u; } v; v.f = f;
    u32 r = (v.u + 0x7fffu + ((v.u >> 16) & 1u)) >> 16;
    return (u16)r;
}
__device__ __forceinline__ float bf2f(u16 h) {
    union { u32 u; float f; } v; v.u = ((u32)h) << 16;
    return v.f;
}
__device__ __forceinline__ f32x4 mfma16(bf16x8 a, bf16x8 b, f32x4 c) {
    return __builtin_amdgcn_mfma_f32_16x16x32_bf16(a, b, c, 0, 0, 0);
}
__device__ __forceinline__ f32x16 mfma32(bf16x8 a, bf16x8 b, f32x16 c) {
    return __builtin_amdgcn_mfma_f32_32x32x16_bf16(a, b, c, 0, 0, 0);
}
// async global->LDS, 16B per lane; lds base must be wave-uniform (HW adds lane*16)
__device__ __forceinline__ void gload16(const u16* g, u16* l) {
    __builtin_amdgcn_global_load_lds(
        (const __attribute__((address_space(1))) u32*)g,
        (__attribute__((address_space(3))) u32*)l, 16, 0, 0);
}
__device__ __forceinline__ u32 pk2(float lo, float hi) {
    __hip_bfloat162 h = __float22bfloat162_rn(make_float2(lo, hi));
    union { __hip_bfloat162 b; u32 u; } cv; cv.b = h; return cv.u;
}
// v_permlane32_swap: a[32:63] <-> b[0:31]
__device__ __forceinline__ void pl32swap(u32& a, u32& b) {
    asm volatile("v_permlane32_swap_b32 %0, %1" : "+v"(a), "+v"(b));
}

// ------- fused prep: wq->bf16, wo->hi/lo, trig table, x transpose+convert -------
__global__ __launch_bounds__(256)
void prep_all(const float* __restrict__ wq, const float* __restrict__ wo,
              const float* __restrict__ fp, const float* __restrict__ x,
              u16* __restrict__ wqh, u16* __restrict__ woh, u16* __restrict__ wol,
              float2* __restrict__ trig, u16* __restrict__ xh)
{
    __shared__ float T[64][65];
    const int b = blockIdx.x, t = threadIdx.x;
    if (b < 512) {                       // wq -> bf16 hi only
        int i = (b * 256 + t) * 4;
        float4 v = *(const float4*)(wq + i);
        ushort4 h;
        h.x = f2bf(v.x); h.y = f2bf(v.y); h.z = f2bf(v.z); h.w = f2bf(v.w);
        *(ushort4*)(wqh + i) = h;
    } else if (b < 1024) {               // wo -> hi/lo split
        int i = ((b - 512) * 256 + t) * 4;
        float4 v = *(const float4*)(wo + i);
        ushort4 h, l;
        h.x = f2bf(v.x); l.x = f2bf(v.x - bf2f(h.x));
        h.y = f2bf(v.y); l.y = f2bf(v.y - bf2f(h.y));
        h.z = f2bf(v.z); l.z = f2bf(v.z - bf2f(h.z));
        h.w = f2bf(v.w); l.w = f2bf(v.w - bf2f(h.w));
        *(ushort4*)(woh + i) = h;
        *(ushort4*)(wol + i) = l;
    } else if (b < 1088) {               // trig: 64 blocks x 256 = 16384 entries
        int idx = (b - 1024) * 256 + t;
        int w = idx >> 4, j = idx & 15;
        float th = (float)w * fp[j];
        float s, c;
        sincosf(th, &s, &c);
        trig[idx] = make_float2(c, s);
    } else {                             // x[bc][h][w] -> x_t[bc][w][h] bf16
        const int b2 = b - 1088;         // 1024 blocks: (8 hb, 16 wb, 8 bc)
        const int h0 = (b2 & 7) * 64, w0 = ((b2 >> 3) & 15) * 64, bc = b2 >> 7;
        {
            const int hl = t >> 2, wc = (t & 3) * 16;
            const float* src = x + ((size_t)bc * F_ + h0 + hl) * W_ + w0 + wc;
            #pragma unroll
            for (int z = 0; z < 4; ++z)
                *(float4*)(&T[hl][wc + z * 4]) = *(const float4*)(src + z * 4);
        }
        __syncthreads();
        {
            const int wl = t >> 2, hc = (t & 3) * 16;
            u16 hv[16];
            #pragma unroll
            for (int z = 0; z < 16; ++z) hv[z] = f2bf(T[hc + z][wl]);
            size_t base = ((size_t)bc * W_ + w0 + wl) * F_ + h0 + hc;
            *(uint4*)(xh + base)     = *(uint4*)(hv);
            *(uint4*)(xh + base + 8) = *(uint4*)(hv + 8);
        }
    }
}

// ---------------- MFMA GEMM, 64x128 tile, dbuf prefetch, explicit drains -------
// D[g][w] = sum_h A[g][h] * Bt[w][h].  4 waves: wm=wid>>1 (M half), wn=wid&1 (N half),
// wave owns 32(M) x 64(N).  Grid (M/64, N/128, BC) = (8,8,8) = 512 blocks -> 2/CU.
// MODE 0: single bf16 pass; writes V raw [bc][g][w] + Q rope'd q_t[bc][head][w][dd]
// MODE 1: split hi/lo 3-pass; writes fp32 out
// LDS buffer (u16): Ah[64][32] @0 | Bh[128][32] @2048 | (MODE1) Al @6144 | Bl @8192
// swizzle: 16B slot ^= (row>>1)&3  (stage source + frag read; 2 lanes/bank = free)
template<int MODE>
__global__ __launch_bounds__(256)
void gemm4(const u16* __restrict__ Ah_, const u16* __restrict__ Al_,
           const u16* __restrict__ Bh_, const u16* __restrict__ Bl_,
           u16* __restrict__ Vout, u16* __restrict__ Qout,
           float* __restrict__ Fout, const float2* __restrict__ trig)
{
    constexpr int BUFS = MODE ? 12288 : 6144;     // u16 per buffer
    __shared__ u16 sh[2 * BUFS];                  // MODE1 48KB, MODE0 24KB

    const int tid = threadIdx.x, lane = tid & 63, wid = tid >> 6;
    const int wm = wid >> 1, wn = wid & 1;
    const int m0 = blockIdx.x * 64, n0 = blockIdx.y * 128, bc = blockIdx.z, c = bc % C_;
    const u16* Abh = Ah_ + (size_t)c * F_ * F_;
    const u16* Abl = MODE ? (Al_ + (size_t)c * F_ * F_) : (const u16*)nullptr;
    const u16* Bbh = Bh_ + (size_t)bc * W_ * F_;
    const u16* Bbl = MODE ? (Bl_ + (size_t)bc * W_ * F_) : (const u16*)nullptr;

    f32x4 acc[2][4] = {};
    const int srow = tid >> 2, sslot = tid & 3;

    auto STAGE = [&](int k0, int buf) {
        u16* base = sh + buf * BUFS;
        {   // A: 64 rows x 4 slots = 256 units (1/lane)
            const int ts = sslot ^ ((srow >> 1) & 3);
            const size_t ga = (size_t)(m0 + srow) * F_ + k0 + ts * 8;
            gload16(Abh + ga, base + wid * 512);
            if constexpr (MODE) gload16(Abl + ga, base + 6144 + wid * 512);
        }
        #pragma unroll
        for (int h = 0; h < 2; ++h) {   // B: 128 rows (2/lane)
            const int brow = h * 64 + srow;
            const int ts = sslot ^ ((brow >> 1) & 3);
            const size_t gb = (size_t)(n0 + brow) * F_ + k0 + ts * 8;
            gload16(Bbh + gb, base + 2048 + h * 2048 + wid * 512);
            if constexpr (MODE) gload16(Bbl + gb, base + 8192 + h * 2048 + wid * 512);
        }
    };

    STAGE(0, 0);
    VDRAIN();                // own DMA landed in buf 0
    __syncthreads();         // publish buf 0
    int cur = 0;
    for (int kt = 0; kt < 16; ++kt) {
        if (kt < 15) STAGE((kt + 1) * 32, cur ^ 1);   // flies during compute
        const u16* Ash = sh + cur * BUFS;
        const u16* Bsh = Ash + 2048;
        const u16* Asl = Ash + 6144;
        const u16* Bsl = Ash + 8192;

        bf16x8 fah[2], fal[2];
        #pragma unroll
        for (int i = 0; i < 2; ++i) {
            const int row = wm * 32 + i * 16 + (lane & 15);
            const int idx = row * 32 + (((lane >> 4) ^ ((row >> 1) & 3)) << 3);
            fah[i] = *(const bf16x8*)(&Ash[idx]);
            if constexpr (MODE) fal[i] = *(const bf16x8*)(&Asl[idx]);
        }
        #pragma unroll
        for (int j = 0; j < 4; ++j) {
            const int rowb = wn * 64 + j * 16 + (lane & 15);
            const int idxb = rowb * 32 + (((lane >> 4) ^ ((rowb >> 1) & 3)) << 3);
            bf16x8 bh = *(const bf16x8*)(&Bsh[idxb]);
            #pragma unroll
            for (int i = 0; i < 2; ++i)
                acc[i][j] = mfma16(fah[i], bh, acc[i][j]);
            if constexpr (MODE) {
                bf16x8 bl = *(const bf16x8*)(&Bsl[idxb]);
                #pragma unroll
                for (int i = 0; i < 2; ++i) {
                    acc[i][j] = mfma16(fah[i], bl, acc[i][j]);
                    acc[i][j] = mfma16(fal[i], bh, acc[i][j]);
                }
            }
        }
        VDRAIN();            // own prefetch landed before buffer becomes readable
        __syncthreads();     // publish cur^1; all reads of cur done
        cur ^= 1;
    }

    // C/D frag: row = (lane>>4)*4 + r, col = lane&15
    #pragma unroll
    for (int i = 0; i < 2; ++i) {
        const int gr = m0 + wm * 32 + i * 16 + (lane >> 4) * 4;
        #pragma unroll
        for (int j = 0; j < 4; ++j) {
            const int wc = n0 + wn * 64 + j * 16 + (lane & 15);
            #pragma unroll
            for (int r = 0; r < 4; ++r) {
                const size_t ad = ((size_t)bc * F_ + gr + r) * W_ + wc;
                if constexpr (MODE == 1) Fout[ad] = acc[i][j][r];
                else                     Vout[ad] = f2bf(acc[i][j][r]);
            }
        }
    }

    if constexpr (MODE == 0) {
        // rope in-register, per-wave LDS transpose (wave owns 32 dd x 64 w),
        // write q_t[bc][head][w][dd].  M-tile (64) == one head: head = blockIdx.x.
        __syncthreads();                      // staging LDS dead
        u16* Qt = sh + wid * 2048;            // [64 w][32 dd], slot ^= wl&3
        const int head = blockIdx.x;
        #pragma unroll
        for (int j = 0; j < 4; ++j) {
            const int wl = j * 16 + (lane & 15);
            const int wg = n0 + wn * 64 + wl;
            #pragma unroll
            for (int i = 0; i < 2; ++i) {
                float q[4];
                if (wm == 0) {                // dd < 32: rotate
                    #pragma unroll
                    for (int p = 0; p < 2; ++p) {
                        const int fidx = i * 8 + (lane >> 4) * 2 + p;
                        float2 cs = trig[wg * NFREQ_ + fidx];
                        float e = acc[i][j][2 * p], o = acc[i][j][2 * p + 1];
                        q[2 * p]     = (e * cs.x - o * cs.y) * QSC_;
                        q[2 * p + 1] = (o * cs.x + e * cs.y) * QSC_;
                    }
                } else {
                    #pragma unroll
                    for (int r = 0; r < 4; ++r) q[r] = acc[i][j][r] * QSC_;
                }
                #pragma unroll
                for (int r = 0; r < 4; ++r) {
                    const int ddl = i * 16 + (lane >> 4) * 4 + r;     // [0,32)
                    Qt[wl * 32 + ((ddl & 7) | (((ddl >> 3) ^ (wl & 3)) << 3))] = f2bf(q[r]);
                }
            }
        }
        // same-wave read-back (compiler orders lgkmcnt), coalesced-ish 16B writes
        const size_t qrow = (((size_t)bc * NH_ + head) * W_ + n0 + wn * 64 + lane) * 64 + wm * 32;
        #pragma unroll
        for (int s = 0; s < 4; ++s) {
            uint4 v = *(const uint4*)(&Qt[lane * 32 + ((s ^ (lane & 3)) << 3)]);
            *(uint4*)(&Qout[qrow + s * 8]) = v;
        }
    }
}

// ---------------- transposed 32x32-MFMA flash attention, dbuf prefetch ----------------
// Qt: [bc][head][w][64] (rope'd, *QSC_; both Q and K). Vg: [bc][g][w] raw.
// S^T = mfma32(K, Q^T); p = exp2(s) (no max-sub, logits bounded ~2);
// O^T = mfma32(V^T, P^T), P^T frags built via cvt_pk + permlane32_swap. No P in LDS.
__global__ __launch_bounds__(256)
void attn3(const u16* __restrict__ Qt, const u16* __restrict__ Vg,
           u16* __restrict__ Ah, u16* __restrict__ Al)
{
    __shared__ u16 sh[16384];      // Ks0|Vs0|Ks1|Vs1, each [64][64] u16, slot^(row&7)
    const int tid = threadIdx.x, lane = tid & 63, wid = tid >> 6;
    const int q0 = blockIdx.x * 128, head = blockIdx.y, bc = blockIdx.z;
    const u16* qb = Qt + ((size_t)bc * NH_ + head) * W_ * 64;
    const u16* vb = Vg + ((size_t)bc * F_ + head * HD_) * W_;

    const int qcol = lane & 31, hi = lane >> 5;
    const int srow = lane >> 3, st = lane & 7;

    // hoisted Q B-frags: lane&31 = q col, d = ks*16 + hi*8 + j
    bf16x8 qf[4];
    {
        const u16* qrow = qb + (size_t)(q0 + wid * 32 + qcol) * 64 + hi * 8;
        #pragma unroll
        for (int ks = 0; ks < 4; ++ks)
            qf[ks] = *(const bf16x8*)(qrow + ks * 16);
    }

    f32x16 o0, o1;
    #pragma unroll
    for (int i = 0; i < 16; ++i) { o0[i] = 0.f; o1[i] = 0.f; }
    float lsum = 0.f;

    auto STAGE = [&](int kt, int buf) {
        const int k0 = kt * 64;
        u16* Ksb = sh + buf * 8192;
        u16* Vsb = Ksb + 4096;
        #pragma unroll
        for (int p = 0; p < 2; ++p) {
            const int rb = wid * 16 + p * 8;          // wave-uniform
            const int r  = rb + srow;
            const int ts = st ^ (r & 7);
            gload16(qb + (size_t)(k0 + r) * 64 + ts * 8, Ksb + rb * 64);
            gload16(vb + (size_t)r * W_ + k0 + ts * 8,   Vsb + rb * 64);
        }
    };

    STAGE(0, 0);
    VDRAIN();                 // own DMA (and qf loads) landed
    __syncthreads();          // publish buf 0
    int cur = 0;
    for (int kt = 0; kt < 16; ++kt) {
        if (kt < 15) STAGE(kt + 1, cur ^ 1);   // flies during compute
        const u16* Ks = sh + cur * 8192;
        const u16* Vs = Ks + 4096;

        // S^T = K . Q^T over d (4 K=16 steps), two 32-k blocks
        f32x16 s0, s1;
        #pragma unroll
        for (int i = 0; i < 16; ++i) { s0[i] = 0.f; s1[i] = 0.f; }
        #pragma unroll
        for (int ks = 0; ks < 4; ++ks) {
            const int sl = ks * 2 + hi;
            const int kA = qcol;
            const int kB = 32 + qcol;
            bf16x8 kf0 = *(const bf16x8*)(Ks + kA * 64 + ((sl ^ (kA & 7)) << 3));
            bf16x8 kf1 = *(const bf16x8*)(Ks + kB * 64 + ((sl ^ (kB & 7)) << 3));
            s0 = mfma32(kf0, qf[ks], s0);
            s1 = mfma32(kf1, qf[ks], s1);
        }

        // p = exp2(s); accumulate denominator
        float p0[16], p1[16];
        #pragma unroll
        for (int i = 0; i < 16; ++i) { p0[i] = EXP2(s0[i]); p1[i] = EXP2(s1[i]); }
        float part = 0.f;
        #pragma unroll
        for (int i = 0; i < 16; ++i) part += p0[i] + p1[i];
        lsum += part;

        // 4 P^T B-frags in-register (cvt_pk + permlane32_swap)
        bf16x8 pf[4];
        #pragma unroll
        for (int kb = 0; kb < 2; ++kb) {
            const float* pp = kb ? p1 : p0;
            #pragma unroll
            for (int f = 0; f < 2; ++f) {
                u32 a1 = pk2(pp[f*8+0], pp[f*8+1]);
                u32 a2 = pk2(pp[f*8+2], pp[f*8+3]);
                u32 b1 = pk2(pp[f*8+4], pp[f*8+5]);
                u32 b2 = pk2(pp[f*8+6], pp[f*8+7]);
                pl32swap(a1, b1);
                pl32swap(a2, b2);
                union { u32 w[4]; bf16x8 v; } u;
                u.w[0] = a1; u.w[1] = a2; u.w[2] = b1; u.w[3] = b2;
                pf[kb * 2 + f] = u.v;
            }
        }

        // O^T += V^T . P^T
        #pragma unroll
        for (int ks2 = 0; ks2 < 4; ++ks2) {
            const int sl = ks2 * 2 + hi;
            const int d0r = qcol;
            const int d1r = 32 + qcol;
            bf16x8 vf0 = *(const bf16x8*)(Vs + d0r * 64 + ((sl ^ (d0r & 7)) << 3));
            bf16x8 vf1 = *(const bf16x8*)(Vs + d1r * 64 + ((sl ^ (d1r & 7)) << 3));
            o0 = mfma32(vf0, pf[ks2], o0);
            o1 = mfma32(vf1, pf[ks2], o1);
        }
        VDRAIN();            // own prefetch landed before buffer becomes readable
        __syncthreads();     // publish cur^1; all reads of cur done
        cur ^= 1;
    }

    lsum += __shfl_xor(lsum, 32);
    const float inv = 1.f / lsum;

    const int wrow = q0 + wid * 32 + qcol;
    const size_t rowbase = ((size_t)bc * W_ + wrow) * F_ + head * HD_;
    #pragma unroll
    for (int dblk = 0; dblk < 2; ++dblk) {
        const f32x16 ov = dblk ? o1 : o0;
        const int coloff = dblk * 32;
        #pragma unroll
        for (int pr = 0; pr < 8; ++pr) {      // reg pair (2pr,2pr+1) -> d rows
            const float v1 = ov[2 * pr]     * inv;
            const float v2 = ov[2 * pr + 1] * inv;
            const int drow = ((2 * pr) & 3) + 8 * (pr >> 1) + 4 * hi;
            const u16 h1 = f2bf(v1), h2 = f2bf(v2);
            const u16 l1 = f2bf(v1 - bf2f(h1)), l2 = f2bf(v2 - bf2f(h2));
            *(u32*)(Ah + rowbase + coloff + drow) = (u32)h1 | ((u32)h2 << 16);
            *(u32*)(Al + rowbase + coloff + drow) = (u32)l1 | ((u32)l2 << 16);
        }
    }
}

extern "C" void kernel_launch(void* const* d_in, const int* in_sizes, int n_in,
                              void* d_out, int out_size, void* d_ws, size_t ws_size,
                              hipStream_t stream) {
    const float* x  = (const float*)d_in[0];
    const float* wq = (const float*)d_in[1];   // reference: q, k, v ALL from wq
    const float* wo = (const float*)d_in[4];
    const float* fp = (const float*)d_in[5];
    float* out = (float*)d_out;

    char* w8 = (char*)d_ws;
    const size_t MB = 1024 * 1024;
    u16* xh   = (u16*)(w8);                    // 8 MB  x_t[bc][w][h] bf16
    u16* wqh  = (u16*)(w8 + 8 * MB);           // 1 MB
    u16* woh  = (u16*)(w8 + 9 * MB);           // 1 MB
    u16* wol  = (u16*)(w8 + 10 * MB);          // 1 MB
    float2* trig = (float2*)(w8 + 11 * MB);    // 128 KB
    u16* qbuf = (u16*)(w8 + 12 * MB);          // 8 MB  q_t[bc][head][w][64]
    u16* vbuf = (u16*)(w8 + 20 * MB);          // 8 MB  v[bc][g][w]
    u16* al   = (u16*)(w8 + 28 * MB);          // 8 MB  a_t lo
    u16* ah   = xh;                            // alias: x_t dead after proj GEMM

    prep_all<<<2112, 256, 0, stream>>>(wq, wo, fp, x, wqh, woh, wol, trig, xh);

    gemm4<0><<<dim3(8, 8, 8), 256, 0, stream>>>(
        wqh, nullptr, xh, nullptr, vbuf, qbuf, nullptr, trig);

    attn3<<<dim3(W_ / 128, NH_, BC_), 256, 0, stream>>>(qbuf, vbuf, ah, al);

    gemm4<1><<<dim3(8, 8, 8), 256, 0, stream>>>(
        woh, wol, ah, al, nullptr, nullptr, out, nullptr);
}